// Round 5
// baseline (9190.918 us; speedup 1.0000x reference)
//
#include <hip/hip_runtime.h>

// ---------------------------------------------------------------------------
// RNN_Layer: x[B,T,C] fp32 -> conv1x1(w_in) -> dense(kernel) -> LSTM(rec)
//            -> dense(w_out).  B=32 T=1024 C=512 D=256 U=256 O=256.
// R5 LSTM: register-resident weights, FORCED via inline-asm pin (R4's compiler
// rematerialized the wr[] loads -> VGPR_Count=64 -> full 512KB/step L2 stream).
// 1 WG (1024 thr) per batch; thread owns one gate-column; 96 of 128 f16 k-pair
// uints resident in VGPRs, 32 streamed from L2 (128KB/step). dot2_f32_f16 MACs,
// readlane h-broadcast. Model: ~2048 cyc/step MAC issue ~= L2 fill -> ~1.3us/step.
// ---------------------------------------------------------------------------

#define DEV static __device__ __forceinline__

typedef __attribute__((ext_vector_type(8))) short short8;
typedef __attribute__((ext_vector_type(4))) float floatx4;
typedef _Float16 half2v __attribute__((ext_vector_type(2)));

static constexpr int Bsz = 32, T = 1024, C = 512, D = 256, U = 256, FU = 1024;
static constexpr int M = Bsz * T;   // 32768 rows for all GEMMs

DEV float bfu2f(unsigned int u) { union { unsigned int i; float f; } v; v.i = u; return v.f; }
DEV float bf2f(unsigned short u) { return bfu2f(((unsigned int)u) << 16); }
DEV unsigned short f2bf(float f) {
    union { float f; unsigned int i; } v; v.f = f;
    return (unsigned short)((v.i + 0x7fffu + ((v.i >> 16) & 1u)) >> 16);
}
DEV float sigmf(float x) { return 1.0f / (1.0f + __expf(-x)); }
DEV float tanhfast(float x) {
    const float a = __expf(-2.0f * fabsf(x));
    const float t = (1.0f - a) / (1.0f + a);
    return copysignf(t, x);
}

// 2-way f16 dot with fp32 accumulate: z += w.lo*a.lo + w.hi*a.hi
DEV float dot2h(unsigned int w, unsigned int a, float acc) {
#if __has_builtin(__builtin_amdgcn_fdot2)
    return __builtin_amdgcn_fdot2(__builtin_bit_cast(half2v, w),
                                  __builtin_bit_cast(half2v, a), acc, false);
#else
    const half2v wv = __builtin_bit_cast(half2v, w);
    const half2v av = __builtin_bit_cast(half2v, a);
    return acc + (float)wv[0] * (float)av[0] + (float)wv[1] * (float)av[1];
#endif
}

// fp32-or-bf16 element -> bf16 bit pattern (GEMM operand loads)
DEV short ld_bf(const float* p) { return (short)f2bf(*p); }
DEV short ld_bf(const unsigned short* p) { return (short)*p; }
DEV short8 ld_frag(const unsigned short* p) { return *(const short8*)p; }
DEV short8 ld_frag(const float* p) {
    short8 v;
#pragma unroll
    for (int j = 0; j < 8; j++) v[j] = (short)f2bf(p[j]);
    return v;
}
DEV float ldxz1(const float* p) { return *p; }
DEV float ldxz1(const unsigned short* p) { return bf2f(*p); }

// ---------------------------------------------------------------------------
// Fragment-direct MFMA GEMM:  C[M,N] = A[M,K] @ B[K,N] + bias[N]
// One wave/block; wave owns NS 16-col strips (B frags in VGPRs), MT row tiles.
// Layouts (m89/m120-verified): A[m=lane&15][k=quad*8+j];
//   B[k=quad*8+j][n=lane&15]; D[m=quad*4+r][n=lane&15]
// ---------------------------------------------------------------------------
template <int K, int N, int MT, int NS, bool OUTF32, typename AT, typename BT>
__global__ __launch_bounds__(64) void gemm_mfma(
    const AT* __restrict__ A,
    const BT* __restrict__ Bm,
    const float* __restrict__ bias,
    void* __restrict__ Cv)
{
    constexpr int KC = K / 32;
    const int lane = threadIdx.x;
    const int quad = lane >> 4, lr = lane & 15;
    constexpr int NSG = N / (16 * NS);
    const int sg = blockIdx.x % NSG;
    const int mb = blockIdx.x / NSG;
    const int n0 = sg * 16 * NS;

    short8 bf[NS][KC];
    float biasv[NS];
#pragma unroll
    for (int s = 0; s < NS; s++) {
        const int n = n0 + s * 16 + lr;
        biasv[s] = bias[n];
#pragma unroll
        for (int kc = 0; kc < KC; kc++) {
            short8 v;
#pragma unroll
            for (int j = 0; j < 8; j++) {
                const int k = kc * 32 + quad * 8 + j;
                v[j] = ld_bf(&Bm[(size_t)k * N + n]);
            }
            bf[s][kc] = v;
        }
    }

    for (int mt = 0; mt < MT; mt++) {
        const int m0 = (mb * MT + mt) * 16;
        const AT* Ap = A + (size_t)(m0 + lr) * K + quad * 8;
        floatx4 acc[NS];
#pragma unroll
        for (int s = 0; s < NS; s++) acc[s] = (floatx4){0.f, 0.f, 0.f, 0.f};
#pragma unroll
        for (int kc = 0; kc < KC; kc++) {
            short8 af = ld_frag(Ap + kc * 32);
#pragma unroll
            for (int s = 0; s < NS; s++)
                acc[s] = __builtin_amdgcn_mfma_f32_16x16x32_bf16(af, bf[s][kc], acc[s], 0, 0, 0);
        }
#pragma unroll
        for (int s = 0; s < NS; s++) {
            const int n = n0 + s * 16 + lr;
#pragma unroll
            for (int r = 0; r < 4; r++) {
                const int m = m0 + quad * 4 + r;
                const float val = acc[s][r] + biasv[s];
                if (OUTF32)
                    ((float*)Cv)[(size_t)m * N + n] = val;
                else
                    ((unsigned short*)Cv)[(size_t)m * N + n] = f2bf(val);
            }
        }
    }
}

// ---------------------------------------------------------------------------
// Pack rec_kernel fp32 [256][1024] -> P[32][1024] uint4 of f16 k-pairs.
// P[g][c].r = pack_f16( W[8g+2r][c], W[8g+2r+1][c] ); kpair kk=4g+r covers
// rows 2kk,2kk+1 of column c.
// ---------------------------------------------------------------------------
__global__ __launch_bounds__(256) void pack_rec(const float* __restrict__ rec,
                                                uint4* __restrict__ P)
{
    const int i = blockIdx.x * 256 + threadIdx.x;    // [0, 32*1024)
    const int g = i >> 10, c = i & 1023;
    uint4 v;
    unsigned int* vp = (unsigned int*)&v;
#pragma unroll
    for (int r = 0; r < 4; r++) {
        const _Float16 lo = (_Float16)rec[(size_t)(8 * g + 2 * r) * FU + c];
        const _Float16 hi = (_Float16)rec[(size_t)(8 * g + 2 * r + 1) * FU + c];
        vp[r] = (unsigned int)__builtin_bit_cast(unsigned short, lo)
              | ((unsigned int)__builtin_bit_cast(unsigned short, hi) << 16);
    }
    P[i] = v;
}

// ---------------------------------------------------------------------------
// LSTM. 1 WG (1024 threads) per batch; thread c owns gate-column c.
//   z[c] = xz[t][c] + sum_k h[k]*W[k][c], via 128 f16 k-pair dot2s.
//   W kpairs 0..95 pinned in VGPRs via opaque asm (prevents load remat);
//   kpairs 96..127 streamed from L2 each step. h as f16 pairs in LDS; lane l
//   holds h[4l..4l+3], broadcast by v_readlane. Keras gate order i,f,g,o.
// ---------------------------------------------------------------------------
template <typename XZT>
__global__ __launch_bounds__(1024, 4) void lstm_kernel(
    const XZT* __restrict__ xz,            // [B, T, 4U]
    const uint4* __restrict__ P,           // packed rec, [32][1024] uint4
    unsigned short* __restrict__ hs)       // [B, T, U] bf16 out
{
    const int b = blockIdx.x;
    const int c = threadIdx.x;
    const int lane = c & 63;
    __shared__ float z_sh[FU];
    __shared__ unsigned short h_pk[U];     // f16 bits of h

    float cst = 0.f;
    if (c < U) h_pk[c] = 0;
    __syncthreads();

    const XZT* xzb = xz + (size_t)b * T * FU;
    unsigned short* hsb = hs + (size_t)b * T * U;
    const uint4* Pc = P + c;

    // resident W: kpairs 0..95 (rows 0..191), 96 VGPRs
    uint4 wr[24];
#pragma unroll
    for (int g = 0; g < 24; g++) wr[g] = Pc[g * 1024];
    // Opaque pin: asm becomes the producer of these 96 values, so the
    // compiler cannot rematerialize the loads inside the t-loop (R4 bug:
    // it did exactly that and streamed 512KB/step from L2).
#pragma unroll
    for (int g = 0; g < 24; g++)
        asm volatile("" : "+v"(wr[g].x), "+v"(wr[g].y), "+v"(wr[g].z), "+v"(wr[g].w));

    float xznext = ldxz1(xzb + c);

#define DO_KP(kk, w) { \
        const unsigned int a_ = (unsigned int)__builtin_amdgcn_readlane( \
            (int)(((kk) & 1) ? hp.y : hp.x), (kk) >> 1); \
        z = dot2h((w), a_, z); }

    for (int t = 0; t < T; t++) {
        float z = xznext;
        // stream part of W: kpairs 96..127, 4-deep window
        uint4 s0 = Pc[24 * 1024];
        uint4 s1 = Pc[25 * 1024];
        uint4 s2 = Pc[26 * 1024];
        uint4 s3 = Pc[27 * 1024];
        if (t + 1 < T) xznext = ldxz1(xzb + (size_t)(t + 1) * FU + c);

        const uint2 hp = *(const uint2*)&h_pk[lane * 4];   // h[4l..4l+3] f16

#pragma unroll
        for (int g = 0; g < 12; g++) {                     // kpairs 0..47
#pragma unroll
            for (int r = 0; r < 4; r++) DO_KP(4 * g + r, wr[g][r]);
        }
#pragma unroll
        for (int r = 0; r < 4; r++) DO_KP(96 + r, s0[r]);  // 96..99
#pragma unroll
        for (int r = 0; r < 4; r++) DO_KP(100 + r, s1[r]); // 100..103
        s0 = Pc[28 * 1024];
        s1 = Pc[29 * 1024];
#pragma unroll
        for (int g = 12; g < 20; g++) {                    // kpairs 48..79
#pragma unroll
            for (int r = 0; r < 4; r++) DO_KP(4 * g + r, wr[g][r]);
        }
#pragma unroll
        for (int r = 0; r < 4; r++) DO_KP(104 + r, s2[r]); // 104..107
#pragma unroll
        for (int r = 0; r < 4; r++) DO_KP(108 + r, s3[r]); // 108..111
        s2 = Pc[30 * 1024];
        s3 = Pc[31 * 1024];
#pragma unroll
        for (int g = 20; g < 24; g++) {                    // kpairs 80..95
#pragma unroll
            for (int r = 0; r < 4; r++) DO_KP(4 * g + r, wr[g][r]);
        }
#pragma unroll
        for (int r = 0; r < 4; r++) DO_KP(112 + r, s0[r]); // 112..115
#pragma unroll
        for (int r = 0; r < 4; r++) DO_KP(116 + r, s1[r]); // 116..119
#pragma unroll
        for (int r = 0; r < 4; r++) DO_KP(120 + r, s2[r]); // 120..123
#pragma unroll
        for (int r = 0; r < 4; r++) DO_KP(124 + r, s3[r]); // 124..127

        z_sh[c] = z;
        __syncthreads();
        if (c < U) {
            const float iv = sigmf(z_sh[c]);
            const float fv = sigmf(z_sh[c + U]);
            const float gv = tanhfast(z_sh[c + 2 * U]);
            const float ov = sigmf(z_sh[c + 3 * U]);
            cst = fv * cst + iv * gv;
            const float hv = ov * tanhfast(cst);
            h_pk[c] = __builtin_bit_cast(unsigned short, (_Float16)hv);
            hsb[(size_t)t * U + c] = f2bf(hv);
        }
        __syncthreads();
    }
#undef DO_KP
}

// ---------------------------------------------------------------------------
extern "C" void kernel_launch(void* const* d_in, const int* in_sizes, int n_in,
                              void* d_out, int out_size, void* d_ws, size_t ws_size,
                              hipStream_t stream)
{
    const float* x    = (const float*)d_in[0];
    const float* w_in = (const float*)d_in[1];
    const float* b_in = (const float*)d_in[2];
    const float* kern = (const float*)d_in[3];
    const float* rec  = (const float*)d_in[4];
    const float* bias = (const float*)d_in[5];
    const float* wout = (const float*)d_in[6];
    const float* bout = (const float*)d_in[7];

    char* ws = (char*)d_ws;
    const size_t rec_bytes = (size_t)32 * 1024 * 16;      // 512 KiB packed W
    const size_t xin_bytes = (size_t)M * D * 2;           // 16 MiB
    const size_t hs_bytes  = (size_t)M * U * 2;           // 16 MiB
    const size_t xz32_bytes = (size_t)M * FU * 4;         // 128 MiB
    const size_t base = rec_bytes + xin_bytes + hs_bytes;

    uint4* P = (uint4*)ws;
    unsigned short* xin_bf = (unsigned short*)(ws + rec_bytes);
    unsigned short* hs_bf  = (unsigned short*)(ws + rec_bytes + xin_bytes);
    char* xz_raw = ws + base;

    const bool use_f32 = ws_size >= base + xz32_bytes;

    // pack rec_kernel -> f16 k-pair tiled layout (every launch; ws re-poisoned)
    pack_rec<<<(32 * 1024) / 256, 256, 0, stream>>>(rec, P);

    // GEMM1: xin = bf16(x @ w_in + b_in)   [M,512]x[512,256]
    gemm_mfma<512, 256, 16, 2, false><<<(256 / 32) * (M / 256), 64, 0, stream>>>(
        x, w_in, b_in, (void*)xin_bf);

    if (use_f32) {
        float* xz = (float*)xz_raw;
        // GEMM2: xz = fp32(xin @ kernel + bias)  [M,256]x[256,1024]
        gemm_mfma<256, 1024, 16, 2, true><<<(1024 / 32) * (M / 256), 64, 0, stream>>>(
            xin_bf, kern, bias, (void*)xz);
        lstm_kernel<float><<<Bsz, 1024, 0, stream>>>(xz, P, hs_bf);
    } else {
        unsigned short* xz = (unsigned short*)xz_raw;
        gemm_mfma<256, 1024, 16, 2, false><<<(1024 / 32) * (M / 256), 64, 0, stream>>>(
            xin_bf, kern, bias, (void*)xz);
        lstm_kernel<unsigned short><<<Bsz, 1024, 0, stream>>>(xz, P, hs_bf);
    }

    // GEMM3: out = fp32(hs @ w_out + b_out)  [M,256]x[256,256]
    gemm_mfma<256, 256, 16, 2, true><<<(256 / 32) * (M / 256), 64, 0, stream>>>(
        hs_bf, wout, bout, d_out);
}

// Round 6
// 2311.105 us; speedup vs baseline: 3.9768x; 3.9768x over previous
//
#include <hip/hip_runtime.h>

// ---------------------------------------------------------------------------
// RNN_Layer: x[B,T,C] fp32 -> conv1x1(w_in) -> dense(kernel) -> LSTM(rec)
//            -> dense(w_out).  B=32 T=1024 C=512 D=256 U=256 O=256.
// R6 LSTM: 512 thr/WG, amdgpu_waves_per_eu(2,2) => 256-VGPR budget (R4/R5:
// compiler targeted 8 waves/SIMD -> 64-reg cap -> remat (R4) / spill (R5)).
// Thread owns 2 gate-columns. W kpairs 0..95 resident in 192 VGPRs (pinned);
// kpairs 96..127 staged once to LDS (128KB) and re-read per step (b128).
// Zero per-step L2 traffic for W. Model ~0.9us/step -> ~1ms LSTM.
// ---------------------------------------------------------------------------

#define DEV static __device__ __forceinline__

typedef __attribute__((ext_vector_type(8))) short short8;
typedef __attribute__((ext_vector_type(4))) float floatx4;
typedef _Float16 half2v __attribute__((ext_vector_type(2)));

static constexpr int Bsz = 32, T = 1024, C = 512, D = 256, U = 256, FU = 1024;
static constexpr int M = Bsz * T;   // 32768 rows for all GEMMs

DEV float bfu2f(unsigned int u) { union { unsigned int i; float f; } v; v.i = u; return v.f; }
DEV float bf2f(unsigned short u) { return bfu2f(((unsigned int)u) << 16); }
DEV unsigned short f2bf(float f) {
    union { float f; unsigned int i; } v; v.f = f;
    return (unsigned short)((v.i + 0x7fffu + ((v.i >> 16) & 1u)) >> 16);
}
DEV float sigmf(float x) { return 1.0f / (1.0f + __expf(-x)); }
DEV float tanhfast(float x) {
    const float a = __expf(-2.0f * fabsf(x));
    const float t = (1.0f - a) / (1.0f + a);
    return copysignf(t, x);
}

// 2-way f16 dot with fp32 accumulate: z += w.lo*a.lo + w.hi*a.hi
DEV float dot2h(unsigned int w, unsigned int a, float acc) {
#if __has_builtin(__builtin_amdgcn_fdot2)
    return __builtin_amdgcn_fdot2(__builtin_bit_cast(half2v, w),
                                  __builtin_bit_cast(half2v, a), acc, false);
#else
    const half2v wv = __builtin_bit_cast(half2v, w);
    const half2v av = __builtin_bit_cast(half2v, a);
    return acc + (float)wv[0] * (float)av[0] + (float)wv[1] * (float)av[1];
#endif
}

// fp32-or-bf16 element -> bf16 bit pattern (GEMM operand loads)
DEV short ld_bf(const float* p) { return (short)f2bf(*p); }
DEV short ld_bf(const unsigned short* p) { return (short)*p; }
DEV short8 ld_frag(const unsigned short* p) { return *(const short8*)p; }
DEV short8 ld_frag(const float* p) {
    short8 v;
#pragma unroll
    for (int j = 0; j < 8; j++) v[j] = (short)f2bf(p[j]);
    return v;
}
DEV float ldxz1(const float* p) { return *p; }
DEV float ldxz1(const unsigned short* p) { return bf2f(*p); }

// ---------------------------------------------------------------------------
// Fragment-direct MFMA GEMM:  C[M,N] = A[M,K] @ B[K,N] + bias[N]
// One wave/block; wave owns NS 16-col strips (B frags in VGPRs), MT row tiles.
// Layouts (m89/m120-verified): A[m=lane&15][k=quad*8+j];
//   B[k=quad*8+j][n=lane&15]; D[m=quad*4+r][n=lane&15]
// ---------------------------------------------------------------------------
template <int K, int N, int MT, int NS, bool OUTF32, typename AT, typename BT>
__global__ __launch_bounds__(64) void gemm_mfma(
    const AT* __restrict__ A,
    const BT* __restrict__ Bm,
    const float* __restrict__ bias,
    void* __restrict__ Cv)
{
    constexpr int KC = K / 32;
    const int lane = threadIdx.x;
    const int quad = lane >> 4, lr = lane & 15;
    constexpr int NSG = N / (16 * NS);
    const int sg = blockIdx.x % NSG;
    const int mb = blockIdx.x / NSG;
    const int n0 = sg * 16 * NS;

    short8 bf[NS][KC];
    float biasv[NS];
#pragma unroll
    for (int s = 0; s < NS; s++) {
        const int n = n0 + s * 16 + lr;
        biasv[s] = bias[n];
#pragma unroll
        for (int kc = 0; kc < KC; kc++) {
            short8 v;
#pragma unroll
            for (int j = 0; j < 8; j++) {
                const int k = kc * 32 + quad * 8 + j;
                v[j] = ld_bf(&Bm[(size_t)k * N + n]);
            }
            bf[s][kc] = v;
        }
    }

    for (int mt = 0; mt < MT; mt++) {
        const int m0 = (mb * MT + mt) * 16;
        const AT* Ap = A + (size_t)(m0 + lr) * K + quad * 8;
        floatx4 acc[NS];
#pragma unroll
        for (int s = 0; s < NS; s++) acc[s] = (floatx4){0.f, 0.f, 0.f, 0.f};
#pragma unroll
        for (int kc = 0; kc < KC; kc++) {
            short8 af = ld_frag(Ap + kc * 32);
#pragma unroll
            for (int s = 0; s < NS; s++)
                acc[s] = __builtin_amdgcn_mfma_f32_16x16x32_bf16(af, bf[s][kc], acc[s], 0, 0, 0);
        }
#pragma unroll
        for (int s = 0; s < NS; s++) {
            const int n = n0 + s * 16 + lr;
#pragma unroll
            for (int r = 0; r < 4; r++) {
                const int m = m0 + quad * 4 + r;
                const float val = acc[s][r] + biasv[s];
                if (OUTF32)
                    ((float*)Cv)[(size_t)m * N + n] = val;
                else
                    ((unsigned short*)Cv)[(size_t)m * N + n] = f2bf(val);
            }
        }
    }
}

// ---------------------------------------------------------------------------
// Pack rec_kernel fp32 [256][1024] -> P[32][1024] uint4 of f16 k-pairs.
// P[g][c].r = pack_f16( W[8g+2r][c], W[8g+2r+1][c] ); kpair kk=4g+r covers
// rows 2kk,2kk+1 of column c.
// ---------------------------------------------------------------------------
__global__ __launch_bounds__(256) void pack_rec(const float* __restrict__ rec,
                                                uint4* __restrict__ P)
{
    const int i = blockIdx.x * 256 + threadIdx.x;    // [0, 32*1024)
    const int g = i >> 10, c = i & 1023;
    uint4 v;
    unsigned int* vp = (unsigned int*)&v;
#pragma unroll
    for (int r = 0; r < 4; r++) {
        const _Float16 lo = (_Float16)rec[(size_t)(8 * g + 2 * r) * FU + c];
        const _Float16 hi = (_Float16)rec[(size_t)(8 * g + 2 * r + 1) * FU + c];
        vp[r] = (unsigned int)__builtin_bit_cast(unsigned short, lo)
              | ((unsigned int)__builtin_bit_cast(unsigned short, hi) << 16);
    }
    P[i] = v;
}

// ---------------------------------------------------------------------------
// LSTM. 1 WG (512 threads, 2 waves/SIMD pinned) per batch; thread owns gate
// columns tid and tid+512.  z[c] = xz[t][c] + sum_k h[k]*W[k][c] via 128 f16
// k-pair dot2s per column.  W kpairs 0..95: 192 VGPRs (asm-pinned).  W kpairs
// 96..127: LDS (128KB), re-read per step as b128 with a 4-deep ring.
// h as f16 pairs; lane l holds h[4l..4l+3], broadcast by v_readlane.
// Keras gate order i,f,g,o; cell state fp32 in threads tid<256.
// ---------------------------------------------------------------------------
template <typename XZT>
__global__ __attribute__((amdgpu_flat_work_group_size(512, 512),
                          amdgpu_waves_per_eu(2, 2)))
void lstm_kernel(
    const XZT* __restrict__ xz,            // [B, T, 4U]
    const uint4* __restrict__ P,           // packed rec, [32][1024] uint4
    unsigned short* __restrict__ hs)       // [B, T, U] bf16 out
{
    const int b = blockIdx.x;
    const int tid = threadIdx.x;
    const int lane = tid & 63;
    const int c0 = tid;
    const int c1 = tid + 512;

    __shared__ uint4 Wl[8 * 1024];         // kpairs 96..127, all 1024 cols: 128KB
    __shared__ float z_sh[FU];
    __shared__ unsigned short h_pk[U];     // f16 bits of h

    // stage streamed W slice into LDS (once)
#pragma unroll
    for (int g = 0; g < 8; g++) {
        Wl[g * 1024 + c0] = P[(size_t)(24 + g) * 1024 + c0];
        Wl[g * 1024 + c1] = P[(size_t)(24 + g) * 1024 + c1];
    }
    float cst = 0.f;
    if (tid < U) h_pk[tid] = 0;

    // resident W: kpairs 0..95 for both columns, 192 VGPRs
    uint4 w0[24], w1[24];
#pragma unroll
    for (int g = 0; g < 24; g++) {
        w0[g] = P[(size_t)g * 1024 + c0];
        w1[g] = P[(size_t)g * 1024 + c1];
    }
    // Opaque pin: make asm the producer so the loads can't be rematerialized
    // inside the t-loop (R4) or spilled wholesale by the occupancy heuristic
    // (R5 — fixed here by waves_per_eu(2,2) giving a 256-reg budget).
#pragma unroll
    for (int g = 0; g < 24; g++) {
        asm volatile("" : "+v"(w0[g].x), "+v"(w0[g].y), "+v"(w0[g].z), "+v"(w0[g].w));
        asm volatile("" : "+v"(w1[g].x), "+v"(w1[g].y), "+v"(w1[g].z), "+v"(w1[g].w));
    }
    __syncthreads();

    const XZT* xzb = xz + (size_t)b * T * FU;
    unsigned short* hsb = hs + (size_t)b * T * U;

    float xz0n = ldxz1(xzb + c0);
    float xz1n = ldxz1(xzb + c1);

#define RL(kk) ((unsigned int)__builtin_amdgcn_readlane( \
        (int)(((kk) & 1) ? hp.y : hp.x), (kk) >> 1))

    for (int t = 0; t < T; t++) {
        // LDS ring preload: slots gg=0..3 (kpairs 96..111)
        uint4 La[4], Lb[4];
#pragma unroll
        for (int s = 0; s < 4; s++) {
            La[s] = Wl[s * 1024 + c0];
            Lb[s] = Wl[s * 1024 + c1];
        }

        float z0 = xz0n, z1 = xz1n;
        if (t + 1 < T) {
            xz0n = ldxz1(xzb + (size_t)(t + 1) * FU + c0);
            xz1n = ldxz1(xzb + (size_t)(t + 1) * FU + c1);
        }

        const uint2 hp = *(const uint2*)&h_pk[lane * 4];   // h[4l..4l+3] f16

#pragma unroll
        for (int blk = 0; blk < 8; blk++) {
            // 3 resident kpair-groups
#pragma unroll
            for (int g = 3 * blk; g < 3 * blk + 3; g++) {
#pragma unroll
                for (int r = 0; r < 4; r++) {
                    const unsigned int a_ = RL(4 * g + r);
                    z0 = dot2h(w0[g][r], a_, z0);
                    z1 = dot2h(w1[g][r], a_, z1);
                }
            }
            // 1 streamed kpair-group from the LDS ring
            {
                const uint4 wa = La[blk & 3], wb = Lb[blk & 3];
#pragma unroll
                for (int r = 0; r < 4; r++) {
                    const unsigned int a_ = RL(96 + 4 * blk + r);
                    z0 = dot2h(wa[r], a_, z0);
                    z1 = dot2h(wb[r], a_, z1);
                }
                if (blk < 4) {
                    La[blk & 3] = Wl[(blk + 4) * 1024 + c0];
                    Lb[blk & 3] = Wl[(blk + 4) * 1024 + c1];
                }
            }
        }

        z_sh[c0] = z0;
        z_sh[c1] = z1;
        __syncthreads();
        if (tid < U) {
            const float iv = sigmf(z_sh[tid]);
            const float fv = sigmf(z_sh[tid + U]);
            const float gv = tanhfast(z_sh[tid + 2 * U]);
            const float ov = sigmf(z_sh[tid + 3 * U]);
            cst = fv * cst + iv * gv;
            const float hv = ov * tanhfast(cst);
            h_pk[tid] = __builtin_bit_cast(unsigned short, (_Float16)hv);
            hsb[(size_t)t * U + tid] = f2bf(hv);
        }
        __syncthreads();
    }
#undef RL
}

// ---------------------------------------------------------------------------
extern "C" void kernel_launch(void* const* d_in, const int* in_sizes, int n_in,
                              void* d_out, int out_size, void* d_ws, size_t ws_size,
                              hipStream_t stream)
{
    const float* x    = (const float*)d_in[0];
    const float* w_in = (const float*)d_in[1];
    const float* b_in = (const float*)d_in[2];
    const float* kern = (const float*)d_in[3];
    const float* rec  = (const float*)d_in[4];
    const float* bias = (const float*)d_in[5];
    const float* wout = (const float*)d_in[6];
    const float* bout = (const float*)d_in[7];

    char* ws = (char*)d_ws;
    const size_t rec_bytes = (size_t)32 * 1024 * 16;      // 512 KiB packed W
    const size_t xin_bytes = (size_t)M * D * 2;           // 16 MiB
    const size_t hs_bytes  = (size_t)M * U * 2;           // 16 MiB
    const size_t xz32_bytes = (size_t)M * FU * 4;         // 128 MiB
    const size_t base = rec_bytes + xin_bytes + hs_bytes;

    uint4* P = (uint4*)ws;
    unsigned short* xin_bf = (unsigned short*)(ws + rec_bytes);
    unsigned short* hs_bf  = (unsigned short*)(ws + rec_bytes + xin_bytes);
    char* xz_raw = ws + base;

    const bool use_f32 = ws_size >= base + xz32_bytes;

    // pack rec_kernel -> f16 k-pair tiled layout (every launch; ws re-poisoned)
    pack_rec<<<(32 * 1024) / 256, 256, 0, stream>>>(rec, P);

    // GEMM1: xin = bf16(x @ w_in + b_in)   [M,512]x[512,256]
    gemm_mfma<512, 256, 16, 2, false><<<(256 / 32) * (M / 256), 64, 0, stream>>>(
        x, w_in, b_in, (void*)xin_bf);

    if (use_f32) {
        float* xz = (float*)xz_raw;
        // GEMM2: xz = fp32(xin @ kernel + bias)  [M,256]x[256,1024]
        gemm_mfma<256, 1024, 16, 2, true><<<(1024 / 32) * (M / 256), 64, 0, stream>>>(
            xin_bf, kern, bias, (void*)xz);
        lstm_kernel<float><<<Bsz, 512, 0, stream>>>(xz, P, hs_bf);
    } else {
        unsigned short* xz = (unsigned short*)xz_raw;
        gemm_mfma<256, 1024, 16, 2, false><<<(1024 / 32) * (M / 256), 64, 0, stream>>>(
            xin_bf, kern, bias, (void*)xz);
        lstm_kernel<unsigned short><<<Bsz, 512, 0, stream>>>(xz, P, hs_bf);
    }

    // GEMM3: out = fp32(hs @ w_out + b_out)  [M,256]x[256,256]
    gemm_mfma<256, 256, 16, 2, true><<<(256 / 32) * (M / 256), 64, 0, stream>>>(
        hs_bf, wout, bout, d_out);
}